// Round 1
// baseline (221.458 us; speedup 1.0000x reference)
//
#include <hip/hip_runtime.h>
#include <math.h>

// Reflection per reference: x+=0.5; x=mod(x,2S); x = x>=S ? 2S-x : x; x-=0.5; clip[0,S-1]
__device__ __forceinline__ float reflect_coord(float x, float size) {
    x += 0.5f;
    float two = 2.0f * size;
    x = x - floorf(x / two) * two;     // jnp.mod (floor-mod, non-negative)
    if (x >= size) x = two - x;
    x -= 0.5f;
    return fminf(fmaxf(x, 0.0f), size - 1.0f);
}

__global__ __launch_bounds__(256) void displace_kernel(
    const float* __restrict__ img,    // N,H,W,3
    const float* __restrict__ dmap,   // N,DH,DW,3
    const float* __restrict__ amp,    // N
    const float* __restrict__ ang,    // N
    float* __restrict__ out,          // N,H,W,3
    int N, int H, int W, int DH, int DW)
{
    long long idx = (long long)blockIdx.x * blockDim.x + threadIdx.x;
    long long total = (long long)N * H * W;
    if (idx >= total) return;

    int w = (int)(idx % W);
    long long t = idx / W;
    int h = (int)(t % H);
    int n = (int)(t / H);

    // ---- displacement map: 2x bilinear upsample (half-pixel centers, clamped edges), channel mean ----
    float sx = (w + 0.5f) * ((float)DW / (float)W) - 0.5f;
    float sy = (h + 0.5f) * ((float)DH / (float)H) - 0.5f;
    float fx = floorf(sx), fy = floorf(sy);
    float tx = sx - fx, ty = sy - fy;
    int dx0 = max(0, min(DW - 1, (int)fx));
    int dx1 = max(0, min(DW - 1, (int)fx + 1));
    int dy0 = max(0, min(DH - 1, (int)fy));
    int dy1 = max(0, min(DH - 1, (int)fy + 1));

    const float* dbase = dmap + (long long)n * DH * DW * 3;
    const float* p00 = dbase + ((long long)dy0 * DW + dx0) * 3;
    const float* p01 = dbase + ((long long)dy0 * DW + dx1) * 3;
    const float* p10 = dbase + ((long long)dy1 * DW + dx0) * 3;
    const float* p11 = dbase + ((long long)dy1 * DW + dx1) * 3;
    float m00 = p00[0] + p00[1] + p00[2];
    float m01 = p01[0] + p01[1] + p01[2];
    float m10 = p10[0] + p10[1] + p10[2];
    float m11 = p11[0] + p11[1] + p11[2];
    float dmv = ((m00 * (1.0f - tx) + m01 * tx) * (1.0f - ty)
               + (m10 * (1.0f - tx) + m11 * tx) * ty) * (1.0f / 3.0f);

    // ---- displacement in normalized grid coords ----
    float a  = amp[n];
    float an = ang[n];
    float sa, ca;
    sincosf(an, &sa, &ca);
    float d   = dmv * a;
    float ddx = ca * d * (2.0f / (float)(W - 1));
    float ddy = sa * d * (2.0f / (float)(H - 1));

    float gx = -1.0f + 2.0f * (float)w / (float)(W - 1) + ddx;
    float gy = -1.0f + 2.0f * (float)h / (float)(H - 1) + ddy;

    // ---- unnormalize (align_corners=False) + reflect ----
    float ix = ((gx + 1.0f) * (float)W - 1.0f) * 0.5f;
    float iy = ((gy + 1.0f) * (float)H - 1.0f) * 0.5f;
    ix = reflect_coord(ix, (float)W);
    iy = reflect_coord(iy, (float)H);

    // ---- bilinear gather from image ----
    float x0f = floorf(ix), y0f = floorf(iy);
    float wx = ix - x0f, wy = iy - y0f;
    int ix0 = min((int)x0f,     W - 1);
    int ix1 = min((int)x0f + 1, W - 1);
    int iy0 = min((int)y0f,     H - 1);
    int iy1 = min((int)y0f + 1, H - 1);

    const float* ibase = img + (long long)n * H * W * 3;
    const float* Ia = ibase + ((long long)iy0 * W + ix0) * 3;
    const float* Ib = ibase + ((long long)iy0 * W + ix1) * 3;
    const float* Ic = ibase + ((long long)iy1 * W + ix0) * 3;
    const float* Id = ibase + ((long long)iy1 * W + ix1) * 3;

    float wa = (1.0f - wx) * (1.0f - wy);
    float wb = wx * (1.0f - wy);
    float wc = (1.0f - wx) * wy;
    float wd = wx * wy;

    float* o = out + idx * 3;
    #pragma unroll
    for (int c = 0; c < 3; ++c) {
        o[c] = Ia[c] * wa + Ib[c] * wb + Ic[c] * wc + Id[c] * wd;
    }
}

extern "C" void kernel_launch(void* const* d_in, const int* in_sizes, int n_in,
                              void* d_out, int out_size, void* d_ws, size_t ws_size,
                              hipStream_t stream) {
    const float* img  = (const float*)d_in[0];
    const float* dmap = (const float*)d_in[1];
    const float* amp  = (const float*)d_in[2];
    const float* ang  = (const float*)d_in[3];
    float* out = (float*)d_out;

    int N = in_sizes[2];
    long long hw  = (long long)in_sizes[0] / ((long long)N * 3);
    int H = (int)llround(sqrt((double)hw));
    int W = H;
    long long dhw = (long long)in_sizes[1] / ((long long)N * 3);
    int DH = (int)llround(sqrt((double)dhw));
    int DW = DH;

    long long total = (long long)N * H * W;
    int block = 256;
    long long grid = (total + block - 1) / block;
    displace_kernel<<<(dim3)(unsigned)grid, block, 0, stream>>>(
        img, dmap, amp, ang, out, N, H, W, DH, DW);
}